// Round 11
// baseline (619.788 us; speedup 1.0000x reference)
//
#include <hip/hip_runtime.h>
#include <hip/hip_bf16.h>
#include <math.h>

// SpatialTransformerBlock on MI355X (gfx950).
// Round 11: attention Q-hoist — Q fragments live in registers for the whole
// kernel; Q is staged (scaled+swizzled) into the K LDS buffer, fragments read
// once, then the buffer is recycled for K tiles. LDS 57->40KB (HD=128, 2->4
// blocks/CU) and 32->24KB (HD=64). __launch_bounds__(256,4) caps VGPR at 128
// to keep 4 waves/SIMD. Rest identical to round 10.

typedef __attribute__((ext_vector_type(8))) short short8;   // 8 bf16 (4 VGPR) MFMA frag
typedef __attribute__((ext_vector_type(4))) float f32x4;    // MFMA accum
typedef unsigned short u16;

#define DEVI __device__ __forceinline__

static constexpr int Bb = 16, Nn = 1024, Dd = 384;
static constexpr int Mm = Bb * Nn;            // 16384 token rows
static constexpr int H1 = 6, H2 = 3, MLPH = 1536;

DEVI float bf2f(u16 u) { return __uint_as_float(((unsigned int)u) << 16); }
DEVI u16 f2bf(float f) {                       // round-nearest-even (manual)
    unsigned int x = __float_as_uint(f);
    return (u16)((x + 0x7fffu + ((x >> 16) & 1u)) >> 16);
}
DEVI u16 f2bf_hw(float f) {                    // hardware cvt path
    __hip_bfloat16 h = __float2bfloat16(f);
    return *(u16*)&h;
}
DEVI float exp2_fast(float x) {
#if __has_builtin(__builtin_amdgcn_exp2f)
    return __builtin_amdgcn_exp2f(x);
#else
    return exp2f(x);
#endif
}
DEVI f32x4 mfma16(short8 a, short8 b, f32x4 c) {
    return __builtin_amdgcn_mfma_f32_16x16x32_bf16(a, b, c, 0, 0, 0);
}
DEVI void gload_lds16(const u16* g, u16* l) {   // global -> LDS, 16B per lane
    __builtin_amdgcn_global_load_lds(
        (const __attribute__((address_space(1))) void*)g,
        (__attribute__((address_space(3))) void*)l, 16, 0, 0);
}

// ---------------- fp32 -> bf16 weight conversion (all 6 weights, one launch) ----
__global__ __launch_bounds__(256) void cvt_all_kernel(
    const float* __restrict__ s0, const float* __restrict__ s1,
    const float* __restrict__ s2, const float* __restrict__ s3,
    const float* __restrict__ s4, const float* __restrict__ s5,
    u16* __restrict__ dst)
{
    constexpr int c1 = 442368, c2 = 589824, c3 = 1032192,
                  c4 = 1179648, c5 = 1769472, c6 = 2359296;
    int i = blockIdx.x * 256 + threadIdx.x;
    if (i >= c6) return;
    float v;
    if (i < c1)      v = s0[i];
    else if (i < c2) v = s1[i - c1];
    else if (i < c3) v = s2[i - c2];
    else if (i < c4) v = s3[i - c3];
    else if (i < c5) v = s4[i - c4];
    else             v = s5[i - c5];
    dst[i] = f2bf(v);
}

// ---------------- LayerNorm: 1 wave per 384-elem row ----------------
__global__ __launch_bounds__(256) void ln_kernel(
    const float* __restrict__ x, const float* __restrict__ g, const float* __restrict__ b,
    u16* __restrict__ out, float* __restrict__ xcopy)
{
    int wave = threadIdx.x >> 6, lane = threadIdx.x & 63;
    int row = blockIdx.x * 4 + wave;
    const float* xr = x + (size_t)row * Dd;
    float v[6], s = 0.f, sq = 0.f;
#pragma unroll
    for (int e = 0; e < 6; ++e) { v[e] = xr[e * 64 + lane]; s += v[e]; }
#pragma unroll
    for (int e = 0; e < 6; ++e) sq += v[e] * v[e];
#pragma unroll
    for (int m = 1; m < 64; m <<= 1) { s += __shfl_xor(s, m, 64); sq += __shfl_xor(sq, m, 64); }
    float mean = s * (1.f / 384.f);
    float var  = sq * (1.f / 384.f) - mean * mean;
    float rs   = rsqrtf(var + 1e-5f);
#pragma unroll
    for (int e = 0; e < 6; ++e) {
        int c = e * 64 + lane;
        out[(size_t)row * Dd + c] = f2bf((v[e] - mean) * rs * g[c] + b[c]);
        if (xcopy) xcopy[(size_t)row * Dd + c] = v[e];
    }
}

// ---------------- GEMM: C = A[M,K](bf16) @ W[wrow0+N, K](bf16)^T + bias ----------------
// 128x128 tile, 4 waves, 4x4 16x16x32 MFMAs per wave, BK=32.
// Staging: global_load_lds dwordx4, linear LDS [128][32], source pre-swizzled
// chunk cg = c ^ ((row>>1)&3); fragment reads apply the same swizzle.
// EPI: 0 = bias -> bf16 ; 1 = bias + exact GELU -> bf16 ; 2 = resid + alpha*(acc+bias) -> f32
// VT: columns n >= nvt0 stored TRANSPOSED into vt[(n-nvt0)*Mm + m] (bf16).
template<int EPI, bool VT>
__global__ __launch_bounds__(256) void gemm_bt(
    const u16* __restrict__ A, int lda,
    const u16* __restrict__ W, int ldw, int wrow0,
    const float* __restrict__ bias, int brow0, int K,
    void* __restrict__ Cout, int ldc,
    const float* __restrict__ resid, float alpha,
    u16* __restrict__ vt, int nvt0)
{
    __shared__ __align__(16) u16 As[128][32];
    __shared__ __align__(16) u16 Bs[128][32];
    const int m0 = blockIdx.x * 128, n0 = blockIdx.y * 128;
    const int tid = threadIdx.x, wv = tid >> 6, lane = tid & 63;
    const int wr = wv >> 1, wc = wv & 1;
    const int rsel = lane & 15, qv = lane >> 4;       // fragment row / chunk select
    const int srow = wv * 32 + (lane >> 2);           // staging row base (+16 for inst 1)
    const int schunk = lane & 3;                      // staging physical chunk

    f32x4 acc[4][4];
#pragma unroll
    for (int i = 0; i < 4; ++i)
#pragma unroll
        for (int j = 0; j < 4; ++j) acc[i][j] = f32x4{0.f, 0.f, 0.f, 0.f};

    for (int kb = 0; kb < K; kb += 32) {
        __syncthreads();
#pragma unroll
        for (int i = 0; i < 2; ++i) {
            int r = srow + i * 16;
            int cg = schunk ^ ((r >> 1) & 3);         // pre-swizzled source chunk
            gload_lds16(&A[(size_t)(m0 + r) * lda + kb + cg * 8],
                        &As[wv * 32 + i * 16][0]);
            gload_lds16(&W[(size_t)(wrow0 + n0 + r) * ldw + kb + cg * 8],
                        &Bs[wv * 32 + i * 16][0]);
        }
        __syncthreads();
        short8 af[4], bfr[4];
#pragma unroll
        for (int i = 0; i < 4; ++i) {
            int row = wr * 64 + i * 16 + rsel;
            af[i] = *(const short8*)&As[row][(qv ^ ((row >> 1) & 3)) * 8];
        }
#pragma unroll
        for (int j = 0; j < 4; ++j) {
            int row = wc * 64 + j * 16 + rsel;
            bfr[j] = *(const short8*)&Bs[row][(qv ^ ((row >> 1) & 3)) * 8];
        }
        __builtin_amdgcn_s_setprio(1);
#pragma unroll
        for (int i = 0; i < 4; ++i)
#pragma unroll
            for (int j = 0; j < 4; ++j) acc[i][j] = mfma16(af[i], bfr[j], acc[i][j]);
        __builtin_amdgcn_s_setprio(0);
    }

    const int rgrp4 = (lane >> 4) * 4, cidx = lane & 15;
#pragma unroll
    for (int i = 0; i < 4; ++i) {
        int mbase = m0 + wr * 64 + i * 16 + rgrp4;
#pragma unroll
        for (int j = 0; j < 4; ++j) {
            int n = n0 + wc * 64 + j * 16 + cidx;
            float bval = bias[brow0 + n];
            float vv[4];
#pragma unroll
            for (int r = 0; r < 4; ++r) vv[r] = acc[i][j][r] + bval;
            if constexpr (EPI == 0) {
                bool tv = false;
                if constexpr (VT) tv = (n >= nvt0);
                if (tv) {
                    u16 pk[4];
#pragma unroll
                    for (int r = 0; r < 4; ++r) pk[r] = f2bf(vv[r]);
                    *(uint2*)&vt[(size_t)(n - nvt0) * Mm + mbase] = *(const uint2*)pk;
                } else {
#pragma unroll
                    for (int r = 0; r < 4; ++r)
                        ((u16*)Cout)[(size_t)(mbase + r) * ldc + n] = f2bf(vv[r]);
                }
            } else if constexpr (EPI == 1) {
#pragma unroll
                for (int r = 0; r < 4; ++r) {
                    float gg = 0.5f * vv[r] * (1.f + erff(vv[r] * 0.70710678118654752f));
                    ((u16*)Cout)[(size_t)(mbase + r) * ldc + n] = f2bf(gg);
                }
            } else {
#pragma unroll
                for (int r = 0; r < 4; ++r)
                    ((float*)Cout)[(size_t)(mbase + r) * ldc + n] =
                        resid[(size_t)(mbase + r) * ldc + n] + alpha * vv[r];
            }
        }
    }
}

// ---------------- fused attention (flash-style, online softmax) ----------------
// Block: 4 waves, 64 Q-rows (16 per wave). 16 KV tiles of 64.
// V pre-transposed in global: VTb[(h*HD+d)*Mm + b*Nn + kv].
// Q-HOIST: Q (pre-scaled by scale*log2e) is staged into the K buffer, each
// lane's fragments are read into registers ONCE, then the buffer is recycled
// for K tiles. Async-STAGE named prefetch regs, lazy max, per-lane l partials.
template<int HD>
__global__ __launch_bounds__(256, 4) void attn_kernel(
    const u16* __restrict__ Qb, int qs,
    const u16* __restrict__ Kb, int ks,
    const u16* __restrict__ VTb,
    u16* __restrict__ Ob, float scale)
{
    constexpr int CH = HD / 8;                  // 16B chunks per K row
    constexpr int NST = HD / 32;                // staging chunks per thread (K and V each)
    constexpr float THR = 11.5415603f;          // defer-max threshold (8 in ln units)
    __shared__ __align__(16) u16 Ks[64][HD];    // Q during prologue, then K tiles
    __shared__ __align__(16) u16 Vs[HD][64];    // [d][kv], swizzled
    __shared__ __align__(16) u16 Ps[4][16][64]; // per-wave P strip, swizzled

    const int q0 = blockIdx.x * 64, h = blockIdx.y, b = blockIdx.z;
    const int tid = threadIdx.x, wv = tid >> 6, lane = tid & 63;
    const int rsel = lane & 15, kgrp = lane >> 4;
    const float scl2 = scale * 1.44269504088896341f;   // scale * log2e

    // ---- prologue: stage scaled Q into Ks, hoist fragments to registers ----
    for (int c = tid; c < 64 * CH; c += 256) {
        int r = c / CH, ch = c % CH, chs = ch ^ (r & 7);
        uint4 qv4 = *(const uint4*)&Qb[(size_t)(b * Nn + q0 + r) * qs + h * HD + ch * 8];
        const u16* e = (const u16*)&qv4;
        u16 sc[8];
#pragma unroll
        for (int j = 0; j < 8; ++j) sc[j] = f2bf_hw(bf2f(e[j]) * scl2);
        *(uint4*)&Ks[r][chs * 8] = *(const uint4*)sc;
    }

    // constant-index prefetch helpers (i must be a literal at each call site)
    auto loadK = [&](int i, int kv0) -> uint4 {
        int c = tid + i * 256; int r = c / CH, ch = c % CH;
        return *(const uint4*)&Kb[(size_t)(b * Nn + kv0 + r) * ks + h * HD + ch * 8];
    };
    auto loadV = [&](int i, int kv0) -> uint4 {
        int c = tid + i * 256; int d = c >> 3, ch = c & 7;
        return *(const uint4*)&VTb[(size_t)(h * HD + d) * Mm + b * Nn + kv0 + ch * 8];
    };
    auto storeK = [&](int i, uint4 val) {
        int c = tid + i * 256; int r = c / CH, ch = c % CH, chs = ch ^ (r & 7);
        *(uint4*)&Ks[r][chs * 8] = val;
    };
    auto storeV = [&](int i, uint4 val) {
        int c = tid + i * 256; int d = c >> 3, ch = c & 7, chs = ch ^ (d & 7);
        *(uint4*)&Vs[d][chs * 8] = val;
    };

    uint4 k0, k1, k2, k3, v0, v1, v2, v3;       // named prefetch registers
    k0 = loadK(0, 0); k1 = loadK(1, 0);
    v0 = loadV(0, 0); v1 = loadV(1, 0);
    if constexpr (NST == 4) {
        k2 = loadK(2, 0); k3 = loadK(3, 0);
        v2 = loadV(2, 0); v3 = loadV(3, 0);
    }

    __syncthreads();                            // Q staging visible
    const int qrow = wv * 16 + rsel;
    short8 qreg[HD / 32];                       // Q fragments in registers
#pragma unroll
    for (int kk = 0; kk < HD / 32; ++kk)
        qreg[kk] = *(const short8*)&Ks[qrow][((4 * kk + kgrp) ^ (qrow & 7)) * 8];
    // loop-top barrier guarantees these reads complete before K overwrites Ks

    float mrow[4], lrow[4];                     // mrow in log2 units; lrow per-lane partial
    f32x4 oacc[HD / 16];
#pragma unroll
    for (int r = 0; r < 4; ++r) { mrow[r] = -INFINITY; lrow[r] = 0.f; }
#pragma unroll
    for (int ct = 0; ct < HD / 16; ++ct) oacc[ct] = f32x4{0.f, 0.f, 0.f, 0.f};

    for (int t = 0; t < Nn / 64; ++t) {
        __syncthreads();                        // prev compute + qreg reads done
        storeK(0, k0); storeK(1, k1);
        storeV(0, v0); storeV(1, v1);
        if constexpr (NST == 4) {
            storeK(2, k2); storeK(3, k3);
            storeV(2, v2); storeV(3, v3);
        }
        __syncthreads();                        // staging visible

        if (t + 1 < Nn / 64) {                  // issue t+1 loads; in flight over compute
            int kv0 = (t + 1) * 64;
            k0 = loadK(0, kv0); k1 = loadK(1, kv0);
            v0 = loadV(0, kv0); v1 = loadV(1, kv0);
            if constexpr (NST == 4) {
                k2 = loadK(2, kv0); k3 = loadK(3, kv0);
                v2 = loadV(2, kv0); v3 = loadV(3, kv0);
            }
        }

        // S = Q K^T  (wave's 16-row strip x 64 kv) — already in log2 units
        f32x4 sacc[4];
#pragma unroll
        for (int ct = 0; ct < 4; ++ct) sacc[ct] = f32x4{0.f, 0.f, 0.f, 0.f};
        __builtin_amdgcn_s_setprio(1);
#pragma unroll
        for (int kk = 0; kk < HD / 32; ++kk) {
#pragma unroll
            for (int ct = 0; ct < 4; ++ct) {
                int krow = ct * 16 + rsel;
                short8 bk = *(const short8*)&Ks[krow][((4 * kk + kgrp) ^ (krow & 7)) * 8];
                sacc[ct] = mfma16(qreg[kk], bk, sacc[ct]);
            }
        }
        __builtin_amdgcn_s_setprio(0);
        // online softmax (log2 domain); D layout: row = 4*kgrp+r, col = ct*16+rsel
#pragma unroll
        for (int r = 0; r < 4; ++r) {
            float s0 = sacc[0][r], s1 = sacc[1][r];
            float s2 = sacc[2][r], s3 = sacc[3][r];
            float pm = fmaxf(fmaxf(s0, s1), fmaxf(s2, s3));   // lane-local max
            if (__any(pm > mrow[r] + THR)) {    // rare: true max reduce + rescale
                float mx = pm;
#pragma unroll
                for (int mk = 1; mk < 16; mk <<= 1) mx = fmaxf(mx, __shfl_xor(mx, mk, 64));
                float mnew = fmaxf(mrow[r], mx);
                float al = exp2_fast(mrow[r] - mnew);
                lrow[r] *= al;
#pragma unroll
                for (int ct = 0; ct < HD / 16; ++ct) oacc[ct][r] *= al;
                mrow[r] = mnew;
            }
            float p0 = exp2_fast(s0 - mrow[r]), p1 = exp2_fast(s1 - mrow[r]);
            float p2 = exp2_fast(s2 - mrow[r]), p3 = exp2_fast(s3 - mrow[r]);
            lrow[r] += (p0 + p1) + (p2 + p3);   // per-lane partial; no shuffles
            int prow = kgrp * 4 + r;
            float pv[4] = {p0, p1, p2, p3};
#pragma unroll
            for (int ct = 0; ct < 4; ++ct) {
                int chs = ((2 * ct + (rsel >> 3)) ^ (prow & 7));
                Ps[wv][prow][chs * 8 + (rsel & 7)] = f2bf_hw(pv[ct]);
            }
        }
        // no barrier: Ps is per-wave; same-wave DS ordering guarantees RAW

        // O += P V
        __builtin_amdgcn_s_setprio(1);
#pragma unroll
        for (int kk = 0; kk < 2; ++kk) {
            short8 ap = *(const short8*)&Ps[wv][rsel][((4 * kk + kgrp) ^ (rsel & 7)) * 8];
#pragma unroll
            for (int ct = 0; ct < HD / 16; ++ct) {
                int vrow = ct * 16 + rsel;
                short8 bv = *(const short8*)&Vs[vrow][((4 * kk + kgrp) ^ (vrow & 7)) * 8];
                oacc[ct] = mfma16(ap, bv, oacc[ct]);
            }
        }
        __builtin_amdgcn_s_setprio(0);
    }

    // final cross-lane l reduction (once, instead of per tile)
#pragma unroll
    for (int r = 0; r < 4; ++r) {
#pragma unroll
        for (int mk = 1; mk < 16; mk <<= 1) lrow[r] += __shfl_xor(lrow[r], mk, 64);
    }

#pragma unroll
    for (int r = 0; r < 4; ++r) {
        float inv = 1.f / lrow[r];
        size_t m = (size_t)(b * Nn + q0 + wv * 16 + kgrp * 4 + r);
#pragma unroll
        for (int ct = 0; ct < HD / 16; ++ct)
            Ob[m * Dd + h * HD + ct * 16 + rsel] = f2bf(oacc[ct][r] * inv);
    }
}

// ---------------- 3x3 weighted stencil on the 32x32 grid ----------------
__global__ __launch_bounds__(256) void stencil_kernel(
    const u16* __restrict__ xs, u16* __restrict__ nb)
{
    int tid = blockIdx.x * 256 + threadIdx.x;   // Mm*48 threads, 8 channels each
    if (tid >= Mm * 48) return;
    int c8 = tid % 48, pos = tid / 48;
    int j = pos & 31, i = (pos >> 5) & 31;
    float acc[8] = {0, 0, 0, 0, 0, 0, 0, 0};
    float wsum = 0.f;
#pragma unroll
    for (int di = -1; di <= 1; ++di) {
#pragma unroll
        for (int dj = -1; dj <= 1; ++dj) {
            int ii = i + di, jj = j + dj;
            if (ii < 0 || ii > 31 || jj < 0 || jj > 31) continue;
            float w = (di != 0 && dj != 0) ? 0.5f : 1.0f;
            uint4 vv = *(const uint4*)&xs[((size_t)pos + (size_t)(di * 32 + dj)) * Dd + c8 * 8];
            const u16* e = (const u16*)&vv;
#pragma unroll
            for (int q = 0; q < 8; ++q) acc[q] += w * bf2f(e[q]);
            wsum += w;
        }
    }
    float invw = 1.f / wsum;
    u16 ov[8];
#pragma unroll
    for (int q = 0; q < 8; ++q) ov[q] = f2bf(acc[q] * invw);
    *(uint4*)&nb[(size_t)pos * Dd + c8 * 8] = *(const uint4*)ov;
}

// ---------------- driver ----------------
extern "C" void kernel_launch(void* const* d_in, const int* in_sizes, int n_in,
                              void* d_out, int out_size, void* d_ws, size_t ws_size,
                              hipStream_t stream) {
    const float* x        = (const float*)d_in[0];
    const float* ln1_g    = (const float*)d_in[1];
    const float* ln1_b    = (const float*)d_in[2];
    const float* attn_wi  = (const float*)d_in[3];
    const float* attn_bi  = (const float*)d_in[4];
    const float* attn_wo  = (const float*)d_in[5];
    const float* attn_bo  = (const float*)d_in[6];
    const float* sln_g    = (const float*)d_in[7];
    const float* sln_b    = (const float*)d_in[8];
    const float* sattn_wi = (const float*)d_in[9];
    const float* sattn_bi = (const float*)d_in[10];
    const float* sattn_wo = (const float*)d_in[11];
    const float* sattn_bo = (const float*)d_in[12];
    const float* ln2_g    = (const float*)d_in[13];
    const float* ln2_b    = (const float*)d_in[14];
    const float* mlp_w1   = (const float*)d_in[15];
    const float* mlp_b1   = (const float*)d_in[16];
    const float* mlp_w2   = (const float*)d_in[17];
    const float* mlp_b2   = (const float*)d_in[18];
    float* out = (float*)d_out;

    char* base = (char*)d_ws;
    size_t off = 0;
    auto take = [&](size_t bytes) -> char* {
        char* p = base + off; off += (bytes + 255) & ~(size_t)255; return p;
    };
    // 6 weight buffers, contiguous (each size is a multiple of 256B)
    u16* wbi1  = (u16*)take((size_t)1152 * 384 * 2);
    u16* wbo1  = (u16*)take((size_t)384 * 384 * 2);
    u16* wbi2  = (u16*)take((size_t)1152 * 384 * 2);
    u16* wbo2  = (u16*)take((size_t)384 * 384 * 2);
    u16* wbm1  = (u16*)take((size_t)MLPH * 384 * 2);
    u16* wbm2  = (u16*)take((size_t)384 * MLPH * 2);
    u16* bufA  = (u16*)take((size_t)Mm * Dd * 2);            // xn / xs / ln2
    u16* bufB  = (u16*)take((size_t)Mm * 1536 * 2);          // see layout below
    u16* bufO  = (u16*)take((size_t)Mm * Dd * 2);            // attention outputs
    // bufB phase 1: [ Q1 K1 (ldc 768) | Vt1 ] ; phase 2: [ q2 | k2 | vt2 | nbuf ];
    // phase 3: mlp hidden (Mm x 1536)
    u16* qkv1 = bufB;
    u16* vt1  = bufB + (size_t)Mm * 768;
    u16* q2   = bufB;
    u16* k2   = bufB + (size_t)Mm * 384;
    u16* vt2  = bufB + (size_t)Mm * 768;
    u16* nbuf = bufB + (size_t)Mm * 1152;
    (void)ws_size; (void)in_sizes; (void)n_in; (void)out_size;

    // weights -> bf16 (single launch; dst = contiguous wbi1..wbm2 region)
    cvt_all_kernel<<<(2359296 + 255) / 256, 256, 0, stream>>>(
        attn_wi, attn_wo, sattn_wi, sattn_wo, mlp_w1, mlp_w2, wbi1);

    // block 1: x = x + MHA(LN(x));  QKV GEMM writes Q,K normal (ldc 768), V transposed
    ln_kernel<<<Mm / 4, 256, 0, stream>>>(x, ln1_g, ln1_b, bufA, out);
    gemm_bt<0, true><<<dim3(Mm / 128, 1152 / 128), 256, 0, stream>>>(
        bufA, Dd, wbi1, Dd, 0, attn_bi, 0, Dd, qkv1, 768, nullptr, 1.f, vt1, 768);
    attn_kernel<64><<<dim3(Nn / 64, H1, Bb), 256, 0, stream>>>(
        qkv1, 768, qkv1 + 384, 768, vt1, bufO, 0.125f);
    gemm_bt<2, false><<<dim3(Mm / 128, Dd / 128), 256, 0, stream>>>(
        bufO, Dd, wbo1, Dd, 0, attn_bo, 0, Dd, out, Dd, out, 1.f, nullptr, 0);

    // block 2: x = x + 0.5 * MHA(xs, nb, nb)
    ln_kernel<<<Mm / 4, 256, 0, stream>>>(out, sln_g, sln_b, bufA, nullptr);
    stencil_kernel<<<(Mm * 48) / 256, 256, 0, stream>>>(bufA, nbuf);
    gemm_bt<0, false><<<dim3(Mm / 128, Dd / 128), 256, 0, stream>>>(
        bufA, Dd, wbi2, Dd, 0, sattn_bi, 0, Dd, q2, Dd, nullptr, 1.f, nullptr, 0);
    gemm_bt<0, true><<<dim3(Mm / 128, 768 / 128), 256, 0, stream>>>(
        nbuf, Dd, wbi2, Dd, 384, sattn_bi, 384, Dd, k2, 384, nullptr, 1.f, vt2, 384);
    attn_kernel<128><<<dim3(Nn / 64, H2, Bb), 256, 0, stream>>>(
        q2, 384, k2, 384, vt2, bufO, 0.088388347648318447f);
    gemm_bt<2, false><<<dim3(Mm / 128, Dd / 128), 256, 0, stream>>>(
        bufO, Dd, wbo2, Dd, 0, sattn_bo, 0, Dd, out, Dd, out, 0.5f, nullptr, 0);

    // MLP: x = x + W2 gelu(W1 LN(x))
    ln_kernel<<<Mm / 4, 256, 0, stream>>>(out, ln2_g, ln2_b, bufA, nullptr);
    gemm_bt<1, false><<<dim3(Mm / 128, MLPH / 128), 256, 0, stream>>>(
        bufA, Dd, wbm1, Dd, 0, mlp_b1, 0, Dd, bufB, MLPH, nullptr, 1.f, nullptr, 0);
    gemm_bt<2, false><<<dim3(Mm / 128, Dd / 128), 256, 0, stream>>>(
        bufB, MLPH, wbm2, MLPH, 0, mlp_b2, 0, MLPH, out, Dd, out, 1.f, nullptr, 0);
}

// Round 12
// 449.396 us; speedup vs baseline: 1.3792x; 1.3792x over previous
//
#include <hip/hip_runtime.h>
#include <hip/hip_bf16.h>
#include <math.h>

// SpatialTransformerBlock on MI355X (gfx950).
// Round 12: fix round-11 regression — __launch_bounds__(256,4) on attention
// forced VGPR 120->64 and spilled all live state (WRITE 12->51MB, FETCH
// 104->275MB, 173µs). Drop the min-waves arg; keep Q-hoist (LDS 57->40KB /
// 32->24KB) + all round-10 softmax optimizations.

typedef __attribute__((ext_vector_type(8))) short short8;   // 8 bf16 (4 VGPR) MFMA frag
typedef __attribute__((ext_vector_type(4))) float f32x4;    // MFMA accum
typedef unsigned short u16;

#define DEVI __device__ __forceinline__

static constexpr int Bb = 16, Nn = 1024, Dd = 384;
static constexpr int Mm = Bb * Nn;            // 16384 token rows
static constexpr int H1 = 6, H2 = 3, MLPH = 1536;

DEVI float bf2f(u16 u) { return __uint_as_float(((unsigned int)u) << 16); }
DEVI u16 f2bf(float f) {                       // round-nearest-even (manual)
    unsigned int x = __float_as_uint(f);
    return (u16)((x + 0x7fffu + ((x >> 16) & 1u)) >> 16);
}
DEVI u16 f2bf_hw(float f) {                    // hardware cvt path
    __hip_bfloat16 h = __float2bfloat16(f);
    return *(u16*)&h;
}
DEVI float exp2_fast(float x) {
#if __has_builtin(__builtin_amdgcn_exp2f)
    return __builtin_amdgcn_exp2f(x);
#else
    return exp2f(x);
#endif
}
DEVI f32x4 mfma16(short8 a, short8 b, f32x4 c) {
    return __builtin_amdgcn_mfma_f32_16x16x32_bf16(a, b, c, 0, 0, 0);
}
DEVI void gload_lds16(const u16* g, u16* l) {   // global -> LDS, 16B per lane
    __builtin_amdgcn_global_load_lds(
        (const __attribute__((address_space(1))) void*)g,
        (__attribute__((address_space(3))) void*)l, 16, 0, 0);
}

// ---------------- fp32 -> bf16 weight conversion (all 6 weights, one launch) ----
__global__ __launch_bounds__(256) void cvt_all_kernel(
    const float* __restrict__ s0, const float* __restrict__ s1,
    const float* __restrict__ s2, const float* __restrict__ s3,
    const float* __restrict__ s4, const float* __restrict__ s5,
    u16* __restrict__ dst)
{
    constexpr int c1 = 442368, c2 = 589824, c3 = 1032192,
                  c4 = 1179648, c5 = 1769472, c6 = 2359296;
    int i = blockIdx.x * 256 + threadIdx.x;
    if (i >= c6) return;
    float v;
    if (i < c1)      v = s0[i];
    else if (i < c2) v = s1[i - c1];
    else if (i < c3) v = s2[i - c2];
    else if (i < c4) v = s3[i - c3];
    else if (i < c5) v = s4[i - c4];
    else             v = s5[i - c5];
    dst[i] = f2bf(v);
}

// ---------------- LayerNorm: 1 wave per 384-elem row ----------------
__global__ __launch_bounds__(256) void ln_kernel(
    const float* __restrict__ x, const float* __restrict__ g, const float* __restrict__ b,
    u16* __restrict__ out, float* __restrict__ xcopy)
{
    int wave = threadIdx.x >> 6, lane = threadIdx.x & 63;
    int row = blockIdx.x * 4 + wave;
    const float* xr = x + (size_t)row * Dd;
    float v[6], s = 0.f, sq = 0.f;
#pragma unroll
    for (int e = 0; e < 6; ++e) { v[e] = xr[e * 64 + lane]; s += v[e]; }
#pragma unroll
    for (int e = 0; e < 6; ++e) sq += v[e] * v[e];
#pragma unroll
    for (int m = 1; m < 64; m <<= 1) { s += __shfl_xor(s, m, 64); sq += __shfl_xor(sq, m, 64); }
    float mean = s * (1.f / 384.f);
    float var  = sq * (1.f / 384.f) - mean * mean;
    float rs   = rsqrtf(var + 1e-5f);
#pragma unroll
    for (int e = 0; e < 6; ++e) {
        int c = e * 64 + lane;
        out[(size_t)row * Dd + c] = f2bf((v[e] - mean) * rs * g[c] + b[c]);
        if (xcopy) xcopy[(size_t)row * Dd + c] = v[e];
    }
}

// ---------------- GEMM: C = A[M,K](bf16) @ W[wrow0+N, K](bf16)^T + bias ----------------
// 128x128 tile, 4 waves, 4x4 16x16x32 MFMAs per wave, BK=32.
// Staging: global_load_lds dwordx4, linear LDS [128][32], source pre-swizzled
// chunk cg = c ^ ((row>>1)&3); fragment reads apply the same swizzle.
// EPI: 0 = bias -> bf16 ; 1 = bias + exact GELU -> bf16 ; 2 = resid + alpha*(acc+bias) -> f32
// VT: columns n >= nvt0 stored TRANSPOSED into vt[(n-nvt0)*Mm + m] (bf16).
template<int EPI, bool VT>
__global__ __launch_bounds__(256) void gemm_bt(
    const u16* __restrict__ A, int lda,
    const u16* __restrict__ W, int ldw, int wrow0,
    const float* __restrict__ bias, int brow0, int K,
    void* __restrict__ Cout, int ldc,
    const float* __restrict__ resid, float alpha,
    u16* __restrict__ vt, int nvt0)
{
    __shared__ __align__(16) u16 As[128][32];
    __shared__ __align__(16) u16 Bs[128][32];
    const int m0 = blockIdx.x * 128, n0 = blockIdx.y * 128;
    const int tid = threadIdx.x, wv = tid >> 6, lane = tid & 63;
    const int wr = wv >> 1, wc = wv & 1;
    const int rsel = lane & 15, qv = lane >> 4;       // fragment row / chunk select
    const int srow = wv * 32 + (lane >> 2);           // staging row base (+16 for inst 1)
    const int schunk = lane & 3;                      // staging physical chunk

    f32x4 acc[4][4];
#pragma unroll
    for (int i = 0; i < 4; ++i)
#pragma unroll
        for (int j = 0; j < 4; ++j) acc[i][j] = f32x4{0.f, 0.f, 0.f, 0.f};

    for (int kb = 0; kb < K; kb += 32) {
        __syncthreads();
#pragma unroll
        for (int i = 0; i < 2; ++i) {
            int r = srow + i * 16;
            int cg = schunk ^ ((r >> 1) & 3);         // pre-swizzled source chunk
            gload_lds16(&A[(size_t)(m0 + r) * lda + kb + cg * 8],
                        &As[wv * 32 + i * 16][0]);
            gload_lds16(&W[(size_t)(wrow0 + n0 + r) * ldw + kb + cg * 8],
                        &Bs[wv * 32 + i * 16][0]);
        }
        __syncthreads();
        short8 af[4], bfr[4];
#pragma unroll
        for (int i = 0; i < 4; ++i) {
            int row = wr * 64 + i * 16 + rsel;
            af[i] = *(const short8*)&As[row][(qv ^ ((row >> 1) & 3)) * 8];
        }
#pragma unroll
        for (int j = 0; j < 4; ++j) {
            int row = wc * 64 + j * 16 + rsel;
            bfr[j] = *(const short8*)&Bs[row][(qv ^ ((row >> 1) & 3)) * 8];
        }
        __builtin_amdgcn_s_setprio(1);
#pragma unroll
        for (int i = 0; i < 4; ++i)
#pragma unroll
            for (int j = 0; j < 4; ++j) acc[i][j] = mfma16(af[i], bfr[j], acc[i][j]);
        __builtin_amdgcn_s_setprio(0);
    }

    const int rgrp4 = (lane >> 4) * 4, cidx = lane & 15;
#pragma unroll
    for (int i = 0; i < 4; ++i) {
        int mbase = m0 + wr * 64 + i * 16 + rgrp4;
#pragma unroll
        for (int j = 0; j < 4; ++j) {
            int n = n0 + wc * 64 + j * 16 + cidx;
            float bval = bias[brow0 + n];
            float vv[4];
#pragma unroll
            for (int r = 0; r < 4; ++r) vv[r] = acc[i][j][r] + bval;
            if constexpr (EPI == 0) {
                bool tv = false;
                if constexpr (VT) tv = (n >= nvt0);
                if (tv) {
                    u16 pk[4];
#pragma unroll
                    for (int r = 0; r < 4; ++r) pk[r] = f2bf(vv[r]);
                    *(uint2*)&vt[(size_t)(n - nvt0) * Mm + mbase] = *(const uint2*)pk;
                } else {
#pragma unroll
                    for (int r = 0; r < 4; ++r)
                        ((u16*)Cout)[(size_t)(mbase + r) * ldc + n] = f2bf(vv[r]);
                }
            } else if constexpr (EPI == 1) {
#pragma unroll
                for (int r = 0; r < 4; ++r) {
                    float gg = 0.5f * vv[r] * (1.f + erff(vv[r] * 0.70710678118654752f));
                    ((u16*)Cout)[(size_t)(mbase + r) * ldc + n] = f2bf(gg);
                }
            } else {
#pragma unroll
                for (int r = 0; r < 4; ++r)
                    ((float*)Cout)[(size_t)(mbase + r) * ldc + n] =
                        resid[(size_t)(mbase + r) * ldc + n] + alpha * vv[r];
            }
        }
    }
}

// ---------------- fused attention (flash-style, online softmax) ----------------
// Block: 4 waves, 64 Q-rows (16 per wave). 16 KV tiles of 64.
// V pre-transposed in global: VTb[(h*HD+d)*Mm + b*Nn + kv].
// Q-HOIST: Q (pre-scaled by scale*log2e) staged into the K buffer, fragments
// read to registers once, buffer recycled for K tiles. NO launch_bounds min
// (round 11's (256,4) forced VGPR->64 and spilled everything).
template<int HD>
__global__ __launch_bounds__(256) void attn_kernel(
    const u16* __restrict__ Qb, int qs,
    const u16* __restrict__ Kb, int ks,
    const u16* __restrict__ VTb,
    u16* __restrict__ Ob, float scale)
{
    constexpr int CH = HD / 8;                  // 16B chunks per K row
    constexpr int NST = HD / 32;                // staging chunks per thread (K and V each)
    constexpr float THR = 11.5415603f;          // defer-max threshold (8 in ln units)
    __shared__ __align__(16) u16 Ks[64][HD];    // Q during prologue, then K tiles
    __shared__ __align__(16) u16 Vs[HD][64];    // [d][kv], swizzled
    __shared__ __align__(16) u16 Ps[4][16][64]; // per-wave P strip, swizzled

    const int q0 = blockIdx.x * 64, h = blockIdx.y, b = blockIdx.z;
    const int tid = threadIdx.x, wv = tid >> 6, lane = tid & 63;
    const int rsel = lane & 15, kgrp = lane >> 4;
    const float scl2 = scale * 1.44269504088896341f;   // scale * log2e

    // ---- prologue: stage scaled Q into Ks, hoist fragments to registers ----
    for (int c = tid; c < 64 * CH; c += 256) {
        int r = c / CH, ch = c % CH, chs = ch ^ (r & 7);
        uint4 qv4 = *(const uint4*)&Qb[(size_t)(b * Nn + q0 + r) * qs + h * HD + ch * 8];
        const u16* e = (const u16*)&qv4;
        u16 sc[8];
#pragma unroll
        for (int j = 0; j < 8; ++j) sc[j] = f2bf_hw(bf2f(e[j]) * scl2);
        *(uint4*)&Ks[r][chs * 8] = *(const uint4*)sc;
    }

    // constant-index prefetch helpers (i must be a literal at each call site)
    auto loadK = [&](int i, int kv0) -> uint4 {
        int c = tid + i * 256; int r = c / CH, ch = c % CH;
        return *(const uint4*)&Kb[(size_t)(b * Nn + kv0 + r) * ks + h * HD + ch * 8];
    };
    auto loadV = [&](int i, int kv0) -> uint4 {
        int c = tid + i * 256; int d = c >> 3, ch = c & 7;
        return *(const uint4*)&VTb[(size_t)(h * HD + d) * Mm + b * Nn + kv0 + ch * 8];
    };
    auto storeK = [&](int i, uint4 val) {
        int c = tid + i * 256; int r = c / CH, ch = c % CH, chs = ch ^ (r & 7);
        *(uint4*)&Ks[r][chs * 8] = val;
    };
    auto storeV = [&](int i, uint4 val) {
        int c = tid + i * 256; int d = c >> 3, ch = c & 7, chs = ch ^ (d & 7);
        *(uint4*)&Vs[d][chs * 8] = val;
    };

    uint4 k0, k1, k2, k3, v0, v1, v2, v3;       // named prefetch registers
    k0 = loadK(0, 0); k1 = loadK(1, 0);
    v0 = loadV(0, 0); v1 = loadV(1, 0);
    if constexpr (NST == 4) {
        k2 = loadK(2, 0); k3 = loadK(3, 0);
        v2 = loadV(2, 0); v3 = loadV(3, 0);
    }

    __syncthreads();                            // Q staging visible
    const int qrow = wv * 16 + rsel;
    short8 qreg[HD / 32];                       // Q fragments in registers
#pragma unroll
    for (int kk = 0; kk < HD / 32; ++kk)
        qreg[kk] = *(const short8*)&Ks[qrow][((4 * kk + kgrp) ^ (qrow & 7)) * 8];
    // loop-top barrier guarantees these reads complete before K overwrites Ks

    float mrow[4], lrow[4];                     // mrow in log2 units; lrow per-lane partial
    f32x4 oacc[HD / 16];
#pragma unroll
    for (int r = 0; r < 4; ++r) { mrow[r] = -INFINITY; lrow[r] = 0.f; }
#pragma unroll
    for (int ct = 0; ct < HD / 16; ++ct) oacc[ct] = f32x4{0.f, 0.f, 0.f, 0.f};

    for (int t = 0; t < Nn / 64; ++t) {
        __syncthreads();                        // prev compute + qreg reads done
        storeK(0, k0); storeK(1, k1);
        storeV(0, v0); storeV(1, v1);
        if constexpr (NST == 4) {
            storeK(2, k2); storeK(3, k3);
            storeV(2, v2); storeV(3, v3);
        }
        __syncthreads();                        // staging visible

        if (t + 1 < Nn / 64) {                  // issue t+1 loads; in flight over compute
            int kv0 = (t + 1) * 64;
            k0 = loadK(0, kv0); k1 = loadK(1, kv0);
            v0 = loadV(0, kv0); v1 = loadV(1, kv0);
            if constexpr (NST == 4) {
                k2 = loadK(2, kv0); k3 = loadK(3, kv0);
                v2 = loadV(2, kv0); v3 = loadV(3, kv0);
            }
        }

        // S = Q K^T  (wave's 16-row strip x 64 kv) — already in log2 units
        f32x4 sacc[4];
#pragma unroll
        for (int ct = 0; ct < 4; ++ct) sacc[ct] = f32x4{0.f, 0.f, 0.f, 0.f};
        __builtin_amdgcn_s_setprio(1);
#pragma unroll
        for (int kk = 0; kk < HD / 32; ++kk) {
#pragma unroll
            for (int ct = 0; ct < 4; ++ct) {
                int krow = ct * 16 + rsel;
                short8 bk = *(const short8*)&Ks[krow][((4 * kk + kgrp) ^ (krow & 7)) * 8];
                sacc[ct] = mfma16(qreg[kk], bk, sacc[ct]);
            }
        }
        __builtin_amdgcn_s_setprio(0);
        // online softmax (log2 domain); D layout: row = 4*kgrp+r, col = ct*16+rsel
#pragma unroll
        for (int r = 0; r < 4; ++r) {
            float s0 = sacc[0][r], s1 = sacc[1][r];
            float s2 = sacc[2][r], s3 = sacc[3][r];
            float pm = fmaxf(fmaxf(s0, s1), fmaxf(s2, s3));   // lane-local max
            if (__any(pm > mrow[r] + THR)) {    // rare: true max reduce + rescale
                float mx = pm;
#pragma unroll
                for (int mk = 1; mk < 16; mk <<= 1) mx = fmaxf(mx, __shfl_xor(mx, mk, 64));
                float mnew = fmaxf(mrow[r], mx);
                float al = exp2_fast(mrow[r] - mnew);
                lrow[r] *= al;
#pragma unroll
                for (int ct = 0; ct < HD / 16; ++ct) oacc[ct][r] *= al;
                mrow[r] = mnew;
            }
            float p0 = exp2_fast(s0 - mrow[r]), p1 = exp2_fast(s1 - mrow[r]);
            float p2 = exp2_fast(s2 - mrow[r]), p3 = exp2_fast(s3 - mrow[r]);
            lrow[r] += (p0 + p1) + (p2 + p3);   // per-lane partial; no shuffles
            int prow = kgrp * 4 + r;
            float pv[4] = {p0, p1, p2, p3};
#pragma unroll
            for (int ct = 0; ct < 4; ++ct) {
                int chs = ((2 * ct + (rsel >> 3)) ^ (prow & 7));
                Ps[wv][prow][chs * 8 + (rsel & 7)] = f2bf_hw(pv[ct]);
            }
        }
        // no barrier: Ps is per-wave; same-wave DS ordering guarantees RAW

        // O += P V
        __builtin_amdgcn_s_setprio(1);
#pragma unroll
        for (int kk = 0; kk < 2; ++kk) {
            short8 ap = *(const short8*)&Ps[wv][rsel][((4 * kk + kgrp) ^ (rsel & 7)) * 8];
#pragma unroll
            for (int ct = 0; ct < HD / 16; ++ct) {
                int vrow = ct * 16 + rsel;
                short8 bv = *(const short8*)&Vs[vrow][((4 * kk + kgrp) ^ (vrow & 7)) * 8];
                oacc[ct] = mfma16(ap, bv, oacc[ct]);
            }
        }
        __builtin_amdgcn_s_setprio(0);
    }

    // final cross-lane l reduction (once, instead of per tile)
#pragma unroll
    for (int r = 0; r < 4; ++r) {
#pragma unroll
        for (int mk = 1; mk < 16; mk <<= 1) lrow[r] += __shfl_xor(lrow[r], mk, 64);
    }

#pragma unroll
    for (int r = 0; r < 4; ++r) {
        float inv = 1.f / lrow[r];
        size_t m = (size_t)(b * Nn + q0 + wv * 16 + kgrp * 4 + r);
#pragma unroll
        for (int ct = 0; ct < HD / 16; ++ct)
            Ob[m * Dd + h * HD + ct * 16 + rsel] = f2bf(oacc[ct][r] * inv);
    }
}

// ---------------- 3x3 weighted stencil on the 32x32 grid ----------------
__global__ __launch_bounds__(256) void stencil_kernel(
    const u16* __restrict__ xs, u16* __restrict__ nb)
{
    int tid = blockIdx.x * 256 + threadIdx.x;   // Mm*48 threads, 8 channels each
    if (tid >= Mm * 48) return;
    int c8 = tid % 48, pos = tid / 48;
    int j = pos & 31, i = (pos >> 5) & 31;
    float acc[8] = {0, 0, 0, 0, 0, 0, 0, 0};
    float wsum = 0.f;
#pragma unroll
    for (int di = -1; di <= 1; ++di) {
#pragma unroll
        for (int dj = -1; dj <= 1; ++dj) {
            int ii = i + di, jj = j + dj;
            if (ii < 0 || ii > 31 || jj < 0 || jj > 31) continue;
            float w = (di != 0 && dj != 0) ? 0.5f : 1.0f;
            uint4 vv = *(const uint4*)&xs[((size_t)pos + (size_t)(di * 32 + dj)) * Dd + c8 * 8];
            const u16* e = (const u16*)&vv;
#pragma unroll
            for (int q = 0; q < 8; ++q) acc[q] += w * bf2f(e[q]);
            wsum += w;
        }
    }
    float invw = 1.f / wsum;
    u16 ov[8];
#pragma unroll
    for (int q = 0; q < 8; ++q) ov[q] = f2bf(acc[q] * invw);
    *(uint4*)&nb[(size_t)pos * Dd + c8 * 8] = *(const uint4*)ov;
}

// ---------------- driver ----------------
extern "C" void kernel_launch(void* const* d_in, const int* in_sizes, int n_in,
                              void* d_out, int out_size, void* d_ws, size_t ws_size,
                              hipStream_t stream) {
    const float* x        = (const float*)d_in[0];
    const float* ln1_g    = (const float*)d_in[1];
    const float* ln1_b    = (const float*)d_in[2];
    const float* attn_wi  = (const float*)d_in[3];
    const float* attn_bi  = (const float*)d_in[4];
    const float* attn_wo  = (const float*)d_in[5];
    const float* attn_bo  = (const float*)d_in[6];
    const float* sln_g    = (const float*)d_in[7];
    const float* sln_b    = (const float*)d_in[8];
    const float* sattn_wi = (const float*)d_in[9];
    const float* sattn_bi = (const float*)d_in[10];
    const float* sattn_wo = (const float*)d_in[11];
    const float* sattn_bo = (const float*)d_in[12];
    const float* ln2_g    = (const float*)d_in[13];
    const float* ln2_b    = (const float*)d_in[14];
    const float* mlp_w1   = (const float*)d_in[15];
    const float* mlp_b1   = (const float*)d_in[16];
    const float* mlp_w2   = (const float*)d_in[17];
    const float* mlp_b2   = (const float*)d_in[18];
    float* out = (float*)d_out;

    char* base = (char*)d_ws;
    size_t off = 0;
    auto take = [&](size_t bytes) -> char* {
        char* p = base + off; off += (bytes + 255) & ~(size_t)255; return p;
    };
    // 6 weight buffers, contiguous (each size is a multiple of 256B)
    u16* wbi1  = (u16*)take((size_t)1152 * 384 * 2);
    u16* wbo1  = (u16*)take((size_t)384 * 384 * 2);
    u16* wbi2  = (u16*)take((size_t)1152 * 384 * 2);
    u16* wbo2  = (u16*)take((size_t)384 * 384 * 2);
    u16* wbm1  = (u16*)take((size_t)MLPH * 384 * 2);
    u16* wbm2  = (u16*)take((size_t)384 * MLPH * 2);
    u16* bufA  = (u16*)take((size_t)Mm * Dd * 2);            // xn / xs / ln2
    u16* bufB  = (u16*)take((size_t)Mm * 1536 * 2);          // see layout below
    u16* bufO  = (u16*)take((size_t)Mm * Dd * 2);            // attention outputs
    // bufB phase 1: [ Q1 K1 (ldc 768) | Vt1 ] ; phase 2: [ q2 | k2 | vt2 | nbuf ];
    // phase 3: mlp hidden (Mm x 1536)
    u16* qkv1 = bufB;
    u16* vt1  = bufB + (size_t)Mm * 768;
    u16* q2   = bufB;
    u16* k2   = bufB + (size_t)Mm * 384;
    u16* vt2  = bufB + (size_t)Mm * 768;
    u16* nbuf = bufB + (size_t)Mm * 1152;
    (void)ws_size; (void)in_sizes; (void)n_in; (void)out_size;

    // weights -> bf16 (single launch; dst = contiguous wbi1..wbm2 region)
    cvt_all_kernel<<<(2359296 + 255) / 256, 256, 0, stream>>>(
        attn_wi, attn_wo, sattn_wi, sattn_wo, mlp_w1, mlp_w2, wbi1);

    // block 1: x = x + MHA(LN(x));  QKV GEMM writes Q,K normal (ldc 768), V transposed
    ln_kernel<<<Mm / 4, 256, 0, stream>>>(x, ln1_g, ln1_b, bufA, out);
    gemm_bt<0, true><<<dim3(Mm / 128, 1152 / 128), 256, 0, stream>>>(
        bufA, Dd, wbi1, Dd, 0, attn_bi, 0, Dd, qkv1, 768, nullptr, 1.f, vt1, 768);
    attn_kernel<64><<<dim3(Nn / 64, H1, Bb), 256, 0, stream>>>(
        qkv1, 768, qkv1 + 384, 768, vt1, bufO, 0.125f);
    gemm_bt<2, false><<<dim3(Mm / 128, Dd / 128), 256, 0, stream>>>(
        bufO, Dd, wbo1, Dd, 0, attn_bo, 0, Dd, out, Dd, out, 1.f, nullptr, 0);

    // block 2: x = x + 0.5 * MHA(xs, nb, nb)
    ln_kernel<<<Mm / 4, 256, 0, stream>>>(out, sln_g, sln_b, bufA, nullptr);
    stencil_kernel<<<(Mm * 48) / 256, 256, 0, stream>>>(bufA, nbuf);
    gemm_bt<0, false><<<dim3(Mm / 128, Dd / 128), 256, 0, stream>>>(
        bufA, Dd, wbi2, Dd, 0, sattn_bi, 0, Dd, q2, Dd, nullptr, 1.f, nullptr, 0);
    gemm_bt<0, true><<<dim3(Mm / 128, 768 / 128), 256, 0, stream>>>(
        nbuf, Dd, wbi2, Dd, 384, sattn_bi, 384, Dd, k2, 384, nullptr, 1.f, vt2, 384);
    attn_kernel<128><<<dim3(Nn / 64, H2, Bb), 256, 0, stream>>>(
        q2, 384, k2, 384, vt2, bufO, 0.088388347648318447f);
    gemm_bt<2, false><<<dim3(Mm / 128, Dd / 128), 256, 0, stream>>>(
        bufO, Dd, wbo2, Dd, 0, sattn_bo, 0, Dd, out, Dd, out, 0.5f, nullptr, 0);

    // MLP: x = x + W2 gelu(W1 LN(x))
    ln_kernel<<<Mm / 4, 256, 0, stream>>>(out, ln2_g, ln2_b, bufA, nullptr);
    gemm_bt<1, false><<<dim3(Mm / 128, MLPH / 128), 256, 0, stream>>>(
        bufA, Dd, wbm1, Dd, 0, mlp_b1, 0, Dd, bufB, MLPH, nullptr, 1.f, nullptr, 0);
    gemm_bt<2, false><<<dim3(Mm / 128, Dd / 128), 256, 0, stream>>>(
        bufB, MLPH, wbm2, MLPH, 0, mlp_b2, 0, MLPH, out, Dd, out, 1.f, nullptr, 0);
}

// Round 13
// 428.791 us; speedup vs baseline: 1.4454x; 1.0481x over previous
//
#include <hip/hip_runtime.h>
#include <hip/hip_bf16.h>
#include <math.h>

// SpatialTransformerBlock on MI355X (gfx950).
// Round 13: GEMM overhaul — BK=64 (halves barrier/vmcnt-drain count per K;
// LDS 32KB, chunk^=row&7 swizzle) + XCD-chunked y-fast block swizzle so the
// ny blocks sharing an A-row-strip run on one XCD (A fetched once, L2-hit).
// Attention identical to round 12 (control: 71.5 µs).

typedef __attribute__((ext_vector_type(8))) short short8;   // 8 bf16 (4 VGPR) MFMA frag
typedef __attribute__((ext_vector_type(4))) float f32x4;    // MFMA accum
typedef unsigned short u16;

#define DEVI __device__ __forceinline__

static constexpr int Bb = 16, Nn = 1024, Dd = 384;
static constexpr int Mm = Bb * Nn;            // 16384 token rows
static constexpr int H1 = 6, H2 = 3, MLPH = 1536;

DEVI float bf2f(u16 u) { return __uint_as_float(((unsigned int)u) << 16); }
DEVI u16 f2bf(float f) {                       // round-nearest-even (manual)
    unsigned int x = __float_as_uint(f);
    return (u16)((x + 0x7fffu + ((x >> 16) & 1u)) >> 16);
}
DEVI u16 f2bf_hw(float f) {                    // hardware cvt path
    __hip_bfloat16 h = __float2bfloat16(f);
    return *(u16*)&h;
}
DEVI float exp2_fast(float x) {
#if __has_builtin(__builtin_amdgcn_exp2f)
    return __builtin_amdgcn_exp2f(x);
#else
    return exp2f(x);
#endif
}
DEVI f32x4 mfma16(short8 a, short8 b, f32x4 c) {
    return __builtin_amdgcn_mfma_f32_16x16x32_bf16(a, b, c, 0, 0, 0);
}
DEVI void gload_lds16(const u16* g, u16* l) {   // global -> LDS, 16B per lane
    __builtin_amdgcn_global_load_lds(
        (const __attribute__((address_space(1))) void*)g,
        (__attribute__((address_space(3))) void*)l, 16, 0, 0);
}

// ---------------- fp32 -> bf16 weight conversion (all 6 weights, one launch) ----
__global__ __launch_bounds__(256) void cvt_all_kernel(
    const float* __restrict__ s0, const float* __restrict__ s1,
    const float* __restrict__ s2, const float* __restrict__ s3,
    const float* __restrict__ s4, const float* __restrict__ s5,
    u16* __restrict__ dst)
{
    constexpr int c1 = 442368, c2 = 589824, c3 = 1032192,
                  c4 = 1179648, c5 = 1769472, c6 = 2359296;
    int i = blockIdx.x * 256 + threadIdx.x;
    if (i >= c6) return;
    float v;
    if (i < c1)      v = s0[i];
    else if (i < c2) v = s1[i - c1];
    else if (i < c3) v = s2[i - c2];
    else if (i < c4) v = s3[i - c3];
    else if (i < c5) v = s4[i - c4];
    else             v = s5[i - c5];
    dst[i] = f2bf(v);
}

// ---------------- LayerNorm: 1 wave per 384-elem row ----------------
__global__ __launch_bounds__(256) void ln_kernel(
    const float* __restrict__ x, const float* __restrict__ g, const float* __restrict__ b,
    u16* __restrict__ out, float* __restrict__ xcopy)
{
    int wave = threadIdx.x >> 6, lane = threadIdx.x & 63;
    int row = blockIdx.x * 4 + wave;
    const float* xr = x + (size_t)row * Dd;
    float v[6], s = 0.f, sq = 0.f;
#pragma unroll
    for (int e = 0; e < 6; ++e) { v[e] = xr[e * 64 + lane]; s += v[e]; }
#pragma unroll
    for (int e = 0; e < 6; ++e) sq += v[e] * v[e];
#pragma unroll
    for (int m = 1; m < 64; m <<= 1) { s += __shfl_xor(s, m, 64); sq += __shfl_xor(sq, m, 64); }
    float mean = s * (1.f / 384.f);
    float var  = sq * (1.f / 384.f) - mean * mean;
    float rs   = rsqrtf(var + 1e-5f);
#pragma unroll
    for (int e = 0; e < 6; ++e) {
        int c = e * 64 + lane;
        out[(size_t)row * Dd + c] = f2bf((v[e] - mean) * rs * g[c] + b[c]);
        if (xcopy) xcopy[(size_t)row * Dd + c] = v[e];
    }
}

// ---------------- GEMM: C = A[M,K](bf16) @ W[wrow0+N, K](bf16)^T + bias ----------------
// 128x128 tile, 4 waves, BK=64 (2 K-slices of 16 MFMAs per staging phase).
// Staging: 4 gload_lds/thread/matrix into linear [128][64] LDS; source chunk
// pre-swizzled cg = c ^ (r&7); fragment reads apply the same XOR (2-way max).
// Block swizzle: hardware dispatch id (x-fastest) remapped XCD-chunked y-fast:
// logical = (bid&7)*(total/8) + bid>>3 ; m = logical/ny, n = logical%ny.
// EPI: 0 = bias -> bf16 ; 1 = bias + exact GELU -> bf16 ; 2 = resid + alpha*(acc+bias) -> f32
// VT: columns n >= nvt0 stored TRANSPOSED into vt[(n-nvt0)*Mm + m] (bf16).
template<int EPI, bool VT>
__global__ __launch_bounds__(256) void gemm_bt(
    const u16* __restrict__ A, int lda,
    const u16* __restrict__ W, int ldw, int wrow0,
    const float* __restrict__ bias, int brow0, int K,
    void* __restrict__ Cout, int ldc,
    const float* __restrict__ resid, float alpha,
    u16* __restrict__ vt, int nvt0)
{
    __shared__ __align__(16) u16 As[128][64];
    __shared__ __align__(16) u16 Bs[128][64];
    const int nx = gridDim.x, ny = gridDim.y;
    const int bid = blockIdx.y * nx + blockIdx.x;     // HW dispatch order (x fastest)
    const int q = (nx * ny) >> 3;                     // total % 8 == 0 for all our grids
    const int logical = (bid & 7) * q + (bid >> 3);   // XCD-chunked, y-fast within chunk
    const int m0 = (logical / ny) * 128, n0 = (logical % ny) * 128;
    const int tid = threadIdx.x, wv = tid >> 6, lane = tid & 63;
    const int wr = wv >> 1, wc = wv & 1;
    const int rsel = lane & 15, qv = lane >> 4;       // fragment row / chunk-group select
    const int srow8 = lane >> 3, schunk = lane & 7;   // staging row-in-span / chunk

    f32x4 acc[4][4];
#pragma unroll
    for (int i = 0; i < 4; ++i)
#pragma unroll
        for (int j = 0; j < 4; ++j) acc[i][j] = f32x4{0.f, 0.f, 0.f, 0.f};

    for (int kb = 0; kb < K; kb += 64) {
        __syncthreads();
#pragma unroll
        for (int i = 0; i < 4; ++i) {                 // each issue: 8 rows x 64 cols
            int r = wv * 32 + i * 8 + srow8;
            int cg = schunk ^ (r & 7);                // pre-swizzled source chunk
            gload_lds16(&A[(size_t)(m0 + r) * lda + kb + cg * 8],
                        &As[wv * 32 + i * 8][0]);
            gload_lds16(&W[(size_t)(wrow0 + n0 + r) * ldw + kb + cg * 8],
                        &Bs[wv * 32 + i * 8][0]);
        }
        __syncthreads();
#pragma unroll
        for (int kk = 0; kk < 2; ++kk) {              // two K=32 slices per staging
            short8 af[4], bfr[4];
#pragma unroll
            for (int i = 0; i < 4; ++i) {
                int row = wr * 64 + i * 16 + rsel;
                af[i] = *(const short8*)&As[row][((kk * 4 + qv) ^ (row & 7)) * 8];
            }
#pragma unroll
            for (int j = 0; j < 4; ++j) {
                int row = wc * 64 + j * 16 + rsel;
                bfr[j] = *(const short8*)&Bs[row][((kk * 4 + qv) ^ (row & 7)) * 8];
            }
            __builtin_amdgcn_s_setprio(1);
#pragma unroll
            for (int i = 0; i < 4; ++i)
#pragma unroll
                for (int j = 0; j < 4; ++j) acc[i][j] = mfma16(af[i], bfr[j], acc[i][j]);
            __builtin_amdgcn_s_setprio(0);
        }
    }

    const int rgrp4 = (lane >> 4) * 4, cidx = lane & 15;
#pragma unroll
    for (int i = 0; i < 4; ++i) {
        int mbase = m0 + wr * 64 + i * 16 + rgrp4;
#pragma unroll
        for (int j = 0; j < 4; ++j) {
            int n = n0 + wc * 64 + j * 16 + cidx;
            float bval = bias[brow0 + n];
            float vv[4];
#pragma unroll
            for (int r = 0; r < 4; ++r) vv[r] = acc[i][j][r] + bval;
            if constexpr (EPI == 0) {
                bool tv = false;
                if constexpr (VT) tv = (n >= nvt0);
                if (tv) {
                    u16 pk[4];
#pragma unroll
                    for (int r = 0; r < 4; ++r) pk[r] = f2bf(vv[r]);
                    *(uint2*)&vt[(size_t)(n - nvt0) * Mm + mbase] = *(const uint2*)pk;
                } else {
#pragma unroll
                    for (int r = 0; r < 4; ++r)
                        ((u16*)Cout)[(size_t)(mbase + r) * ldc + n] = f2bf(vv[r]);
                }
            } else if constexpr (EPI == 1) {
#pragma unroll
                for (int r = 0; r < 4; ++r) {
                    float gg = 0.5f * vv[r] * (1.f + erff(vv[r] * 0.70710678118654752f));
                    ((u16*)Cout)[(size_t)(mbase + r) * ldc + n] = f2bf(gg);
                }
            } else {
#pragma unroll
                for (int r = 0; r < 4; ++r)
                    ((float*)Cout)[(size_t)(mbase + r) * ldc + n] =
                        resid[(size_t)(mbase + r) * ldc + n] + alpha * vv[r];
            }
        }
    }
}

// ---------------- fused attention (flash-style, online softmax) ----------------
// Identical to round 12 (control). Q-hoist, async-STAGE named regs, lazy max,
// log2 softmax, per-lane l partials, setprio around MFMA clusters.
template<int HD>
__global__ __launch_bounds__(256) void attn_kernel(
    const u16* __restrict__ Qb, int qs,
    const u16* __restrict__ Kb, int ks,
    const u16* __restrict__ VTb,
    u16* __restrict__ Ob, float scale)
{
    constexpr int CH = HD / 8;                  // 16B chunks per K row
    constexpr int NST = HD / 32;                // staging chunks per thread (K and V each)
    constexpr float THR = 11.5415603f;          // defer-max threshold (8 in ln units)
    __shared__ __align__(16) u16 Ks[64][HD];    // Q during prologue, then K tiles
    __shared__ __align__(16) u16 Vs[HD][64];    // [d][kv], swizzled
    __shared__ __align__(16) u16 Ps[4][16][64]; // per-wave P strip, swizzled

    const int q0 = blockIdx.x * 64, h = blockIdx.y, b = blockIdx.z;
    const int tid = threadIdx.x, wv = tid >> 6, lane = tid & 63;
    const int rsel = lane & 15, kgrp = lane >> 4;
    const float scl2 = scale * 1.44269504088896341f;   // scale * log2e

    // ---- prologue: stage scaled Q into Ks, hoist fragments to registers ----
    for (int c = tid; c < 64 * CH; c += 256) {
        int r = c / CH, ch = c % CH, chs = ch ^ (r & 7);
        uint4 qv4 = *(const uint4*)&Qb[(size_t)(b * Nn + q0 + r) * qs + h * HD + ch * 8];
        const u16* e = (const u16*)&qv4;
        u16 sc[8];
#pragma unroll
        for (int j = 0; j < 8; ++j) sc[j] = f2bf_hw(bf2f(e[j]) * scl2);
        *(uint4*)&Ks[r][chs * 8] = *(const uint4*)sc;
    }

    // constant-index prefetch helpers (i must be a literal at each call site)
    auto loadK = [&](int i, int kv0) -> uint4 {
        int c = tid + i * 256; int r = c / CH, ch = c % CH;
        return *(const uint4*)&Kb[(size_t)(b * Nn + kv0 + r) * ks + h * HD + ch * 8];
    };
    auto loadV = [&](int i, int kv0) -> uint4 {
        int c = tid + i * 256; int d = c >> 3, ch = c & 7;
        return *(const uint4*)&VTb[(size_t)(h * HD + d) * Mm + b * Nn + kv0 + ch * 8];
    };
    auto storeK = [&](int i, uint4 val) {
        int c = tid + i * 256; int r = c / CH, ch = c % CH, chs = ch ^ (r & 7);
        *(uint4*)&Ks[r][chs * 8] = val;
    };
    auto storeV = [&](int i, uint4 val) {
        int c = tid + i * 256; int d = c >> 3, ch = c & 7, chs = ch ^ (d & 7);
        *(uint4*)&Vs[d][chs * 8] = val;
    };

    uint4 k0, k1, k2, k3, v0, v1, v2, v3;       // named prefetch registers
    k0 = loadK(0, 0); k1 = loadK(1, 0);
    v0 = loadV(0, 0); v1 = loadV(1, 0);
    if constexpr (NST == 4) {
        k2 = loadK(2, 0); k3 = loadK(3, 0);
        v2 = loadV(2, 0); v3 = loadV(3, 0);
    }

    __syncthreads();                            // Q staging visible
    const int qrow = wv * 16 + rsel;
    short8 qreg[HD / 32];                       // Q fragments in registers
#pragma unroll
    for (int kk = 0; kk < HD / 32; ++kk)
        qreg[kk] = *(const short8*)&Ks[qrow][((4 * kk + kgrp) ^ (qrow & 7)) * 8];
    // loop-top barrier guarantees these reads complete before K overwrites Ks

    float mrow[4], lrow[4];                     // mrow in log2 units; lrow per-lane partial
    f32x4 oacc[HD / 16];
#pragma unroll
    for (int r = 0; r < 4; ++r) { mrow[r] = -INFINITY; lrow[r] = 0.f; }
#pragma unroll
    for (int ct = 0; ct < HD / 16; ++ct) oacc[ct] = f32x4{0.f, 0.f, 0.f, 0.f};

    for (int t = 0; t < Nn / 64; ++t) {
        __syncthreads();                        // prev compute + qreg reads done
        storeK(0, k0); storeK(1, k1);
        storeV(0, v0); storeV(1, v1);
        if constexpr (NST == 4) {
            storeK(2, k2); storeK(3, k3);
            storeV(2, v2); storeV(3, v3);
        }
        __syncthreads();                        // staging visible

        if (t + 1 < Nn / 64) {                  // issue t+1 loads; in flight over compute
            int kv0 = (t + 1) * 64;
            k0 = loadK(0, kv0); k1 = loadK(1, kv0);
            v0 = loadV(0, kv0); v1 = loadV(1, kv0);
            if constexpr (NST == 4) {
                k2 = loadK(2, kv0); k3 = loadK(3, kv0);
                v2 = loadV(2, kv0); v3 = loadV(3, kv0);
            }
        }

        // S = Q K^T  (wave's 16-row strip x 64 kv) — already in log2 units
        f32x4 sacc[4];
#pragma unroll
        for (int ct = 0; ct < 4; ++ct) sacc[ct] = f32x4{0.f, 0.f, 0.f, 0.f};
        __builtin_amdgcn_s_setprio(1);
#pragma unroll
        for (int kk = 0; kk < HD / 32; ++kk) {
#pragma unroll
            for (int ct = 0; ct < 4; ++ct) {
                int krow = ct * 16 + rsel;
                short8 bk = *(const short8*)&Ks[krow][((4 * kk + kgrp) ^ (krow & 7)) * 8];
                sacc[ct] = mfma16(qreg[kk], bk, sacc[ct]);
            }
        }
        __builtin_amdgcn_s_setprio(0);
        // online softmax (log2 domain); D layout: row = 4*kgrp+r, col = ct*16+rsel
#pragma unroll
        for (int r = 0; r < 4; ++r) {
            float s0 = sacc[0][r], s1 = sacc[1][r];
            float s2 = sacc[2][r], s3 = sacc[3][r];
            float pm = fmaxf(fmaxf(s0, s1), fmaxf(s2, s3));   // lane-local max
            if (__any(pm > mrow[r] + THR)) {    // rare: true max reduce + rescale
                float mx = pm;
#pragma unroll
                for (int mk = 1; mk < 16; mk <<= 1) mx = fmaxf(mx, __shfl_xor(mx, mk, 64));
                float mnew = fmaxf(mrow[r], mx);
                float al = exp2_fast(mrow[r] - mnew);
                lrow[r] *= al;
#pragma unroll
                for (int ct = 0; ct < HD / 16; ++ct) oacc[ct][r] *= al;
                mrow[r] = mnew;
            }
            float p0 = exp2_fast(s0 - mrow[r]), p1 = exp2_fast(s1 - mrow[r]);
            float p2 = exp2_fast(s2 - mrow[r]), p3 = exp2_fast(s3 - mrow[r]);
            lrow[r] += (p0 + p1) + (p2 + p3);   // per-lane partial; no shuffles
            int prow = kgrp * 4 + r;
            float pv[4] = {p0, p1, p2, p3};
#pragma unroll
            for (int ct = 0; ct < 4; ++ct) {
                int chs = ((2 * ct + (rsel >> 3)) ^ (prow & 7));
                Ps[wv][prow][chs * 8 + (rsel & 7)] = f2bf_hw(pv[ct]);
            }
        }
        // no barrier: Ps is per-wave; same-wave DS ordering guarantees RAW

        // O += P V
        __builtin_amdgcn_s_setprio(1);
#pragma unroll
        for (int kk = 0; kk < 2; ++kk) {
            short8 ap = *(const short8*)&Ps[wv][rsel][((4 * kk + kgrp) ^ (rsel & 7)) * 8];
#pragma unroll
            for (int ct = 0; ct < HD / 16; ++ct) {
                int vrow = ct * 16 + rsel;
                short8 bv = *(const short8*)&Vs[vrow][((4 * kk + kgrp) ^ (vrow & 7)) * 8];
                oacc[ct] = mfma16(ap, bv, oacc[ct]);
            }
        }
        __builtin_amdgcn_s_setprio(0);
    }

    // final cross-lane l reduction (once, instead of per tile)
#pragma unroll
    for (int r = 0; r < 4; ++r) {
#pragma unroll
        for (int mk = 1; mk < 16; mk <<= 1) lrow[r] += __shfl_xor(lrow[r], mk, 64);
    }

#pragma unroll
    for (int r = 0; r < 4; ++r) {
        float inv = 1.f / lrow[r];
        size_t m = (size_t)(b * Nn + q0 + wv * 16 + kgrp * 4 + r);
#pragma unroll
        for (int ct = 0; ct < HD / 16; ++ct)
            Ob[m * Dd + h * HD + ct * 16 + rsel] = f2bf(oacc[ct][r] * inv);
    }
}

// ---------------- 3x3 weighted stencil on the 32x32 grid ----------------
__global__ __launch_bounds__(256) void stencil_kernel(
    const u16* __restrict__ xs, u16* __restrict__ nb)
{
    int tid = blockIdx.x * 256 + threadIdx.x;   // Mm*48 threads, 8 channels each
    if (tid >= Mm * 48) return;
    int c8 = tid % 48, pos = tid / 48;
    int j = pos & 31, i = (pos >> 5) & 31;
    float acc[8] = {0, 0, 0, 0, 0, 0, 0, 0};
    float wsum = 0.f;
#pragma unroll
    for (int di = -1; di <= 1; ++di) {
#pragma unroll
        for (int dj = -1; dj <= 1; ++dj) {
            int ii = i + di, jj = j + dj;
            if (ii < 0 || ii > 31 || jj < 0 || jj > 31) continue;
            float w = (di != 0 && dj != 0) ? 0.5f : 1.0f;
            uint4 vv = *(const uint4*)&xs[((size_t)pos + (size_t)(di * 32 + dj)) * Dd + c8 * 8];
            const u16* e = (const u16*)&vv;
#pragma unroll
            for (int q = 0; q < 8; ++q) acc[q] += w * bf2f(e[q]);
            wsum += w;
        }
    }
    float invw = 1.f / wsum;
    u16 ov[8];
#pragma unroll
    for (int q = 0; q < 8; ++q) ov[q] = f2bf(acc[q] * invw);
    *(uint4*)&nb[(size_t)pos * Dd + c8 * 8] = *(const uint4*)ov;
}

// ---------------- driver ----------------
extern "C" void kernel_launch(void* const* d_in, const int* in_sizes, int n_in,
                              void* d_out, int out_size, void* d_ws, size_t ws_size,
                              hipStream_t stream) {
    const float* x        = (const float*)d_in[0];
    const float* ln1_g    = (const float*)d_in[1];
    const float* ln1_b    = (const float*)d_in[2];
    const float* attn_wi  = (const float*)d_in[3];
    const float* attn_bi  = (const float*)d_in[4];
    const float* attn_wo  = (const float*)d_in[5];
    const float* attn_bo  = (const float*)d_in[6];
    const float* sln_g    = (const float*)d_in[7];
    const float* sln_b    = (const float*)d_in[8];
    const float* sattn_wi = (const float*)d_in[9];
    const float* sattn_bi = (const float*)d_in[10];
    const float* sattn_wo = (const float*)d_in[11];
    const float* sattn_bo = (const float*)d_in[12];
    const float* ln2_g    = (const float*)d_in[13];
    const float* ln2_b    = (const float*)d_in[14];
    const float* mlp_w1   = (const float*)d_in[15];
    const float* mlp_b1   = (const float*)d_in[16];
    const float* mlp_w2   = (const float*)d_in[17];
    const float* mlp_b2   = (const float*)d_in[18];
    float* out = (float*)d_out;

    char* base = (char*)d_ws;
    size_t off = 0;
    auto take = [&](size_t bytes) -> char* {
        char* p = base + off; off += (bytes + 255) & ~(size_t)255; return p;
    };
    // 6 weight buffers, contiguous (each size is a multiple of 256B)
    u16* wbi1  = (u16*)take((size_t)1152 * 384 * 2);
    u16* wbo1  = (u16*)take((size_t)384 * 384 * 2);
    u16* wbi2  = (u16*)take((size_t)1152 * 384 * 2);
    u16* wbo2  = (u16*)take((size_t)384 * 384 * 2);
    u16* wbm1  = (u16*)take((size_t)MLPH * 384 * 2);
    u16* wbm2  = (u16*)take((size_t)384 * MLPH * 2);
    u16* bufA  = (u16*)take((size_t)Mm * Dd * 2);            // xn / xs / ln2
    u16* bufB  = (u16*)take((size_t)Mm * 1536 * 2);          // see layout below
    u16* bufO  = (u16*)take((size_t)Mm * Dd * 2);            // attention outputs
    // bufB phase 1: [ Q1 K1 (ldc 768) | Vt1 ] ; phase 2: [ q2 | k2 | vt2 | nbuf ];
    // phase 3: mlp hidden (Mm x 1536)
    u16* qkv1 = bufB;
    u16* vt1  = bufB + (size_t)Mm * 768;
    u16* q2   = bufB;
    u16* k2   = bufB + (size_t)Mm * 384;
    u16* vt2  = bufB + (size_t)Mm * 768;
    u16* nbuf = bufB + (size_t)Mm * 1152;
    (void)ws_size; (void)in_sizes; (void)n_in; (void)out_size;

    // weights -> bf16 (single launch; dst = contiguous wbi1..wbm2 region)
    cvt_all_kernel<<<(2359296 + 255) / 256, 256, 0, stream>>>(
        attn_wi, attn_wo, sattn_wi, sattn_wo, mlp_w1, mlp_w2, wbi1);

    // block 1: x = x + MHA(LN(x));  QKV GEMM writes Q,K normal (ldc 768), V transposed
    ln_kernel<<<Mm / 4, 256, 0, stream>>>(x, ln1_g, ln1_b, bufA, out);
    gemm_bt<0, true><<<dim3(Mm / 128, 1152 / 128), 256, 0, stream>>>(
        bufA, Dd, wbi1, Dd, 0, attn_bi, 0, Dd, qkv1, 768, nullptr, 1.f, vt1, 768);
    attn_kernel<64><<<dim3(Nn / 64, H1, Bb), 256, 0, stream>>>(
        qkv1, 768, qkv1 + 384, 768, vt1, bufO, 0.125f);
    gemm_bt<2, false><<<dim3(Mm / 128, Dd / 128), 256, 0, stream>>>(
        bufO, Dd, wbo1, Dd, 0, attn_bo, 0, Dd, out, Dd, out, 1.f, nullptr, 0);

    // block 2: x = x + 0.5 * MHA(xs, nb, nb)
    ln_kernel<<<Mm / 4, 256, 0, stream>>>(out, sln_g, sln_b, bufA, nullptr);
    stencil_kernel<<<(Mm * 48) / 256, 256, 0, stream>>>(bufA, nbuf);
    gemm_bt<0, false><<<dim3(Mm / 128, Dd / 128), 256, 0, stream>>>(
        bufA, Dd, wbi2, Dd, 0, sattn_bi, 0, Dd, q2, Dd, nullptr, 1.f, nullptr, 0);
    gemm_bt<0, true><<<dim3(Mm / 128, 768 / 128), 256, 0, stream>>>(
        nbuf, Dd, wbi2, Dd, 384, sattn_bi, 384, Dd, k2, 384, nullptr, 1.f, vt2, 384);
    attn_kernel<128><<<dim3(Nn / 64, H2, Bb), 256, 0, stream>>>(
        q2, 384, k2, 384, vt2, bufO, 0.088388347648318447f);
    gemm_bt<2, false><<<dim3(Mm / 128, Dd / 128), 256, 0, stream>>>(
        bufO, Dd, wbo2, Dd, 0, sattn_bo, 0, Dd, out, Dd, out, 0.5f, nullptr, 0);

    // MLP: x = x + W2 gelu(W1 LN(x))
    ln_kernel<<<Mm / 4, 256, 0, stream>>>(out, ln2_g, ln2_b, bufA, nullptr);
    gemm_bt<1, false><<<dim3(Mm / 128, MLPH / 128), 256, 0, stream>>>(
        bufA, Dd, wbm1, Dd, 0, mlp_b1, 0, Dd, bufB, MLPH, nullptr, 1.f, nullptr, 0);
    gemm_bt<2, false><<<dim3(Mm / 128, Dd / 128), 256, 0, stream>>>(
        bufB, MLPH, wbm2, MLPH, 0, mlp_b2, 0, MLPH, out, Dd, out, 1.f, nullptr, 0);
}